// Round 5
// baseline (64.777 us; speedup 1.0000x reference)
//
#include <hip/hip_runtime.h>
#include <hip/hip_bf16.h>

#define IN_DIM  512
#define OUT_DIM 512
#define BATCH   4096
#define NBASIS  9
#define KDIM    4608            // permuted: k' = i*8+j (j=0..7 splines), 4096+i = silu
#define SPLITK  4
#define KSPLIT  1152

// ws layout (bytes)
#define WOFF_WBF  0
#define WSZ_WBF   (OUT_DIM * KDIM * 2)                  // 4,718,592 (permuted bf16 W)
#define WOFF_PART (WOFF_WBF + WSZ_WBF)
#define WSZ_PART  (SPLITK * BATCH * OUT_DIM * 2)        // 16,777,216 (fp16 partials)
#define WOFF_TBL  (WOFF_PART + WSZ_PART)                // 512 float2 = 4 KB

typedef __attribute__((ext_vector_type(8))) short bf16x8;
typedef __attribute__((ext_vector_type(4))) float f32x4;
typedef __attribute__((ext_vector_type(8))) _Float16 h16x8;

__device__ __forceinline__ unsigned long long pack4(float a, float b, float c, float d) {
    __hip_bfloat16 ha = __float2bfloat16(a), hb = __float2bfloat16(b),
                   hc = __float2bfloat16(c), hd = __float2bfloat16(d);
    return  (unsigned long long)*reinterpret_cast<unsigned short*>(&ha)
         | ((unsigned long long)*reinterpret_cast<unsigned short*>(&hb) << 16)
         | ((unsigned long long)*reinterpret_cast<unsigned short*>(&hc) << 32)
         | ((unsigned long long)*reinterpret_cast<unsigned short*>(&hd) << 48);
}

__device__ __forceinline__ float silux(float z) {     // silu(z)*z
    return z * z / (1.0f + __expf(-z));
}

// ---------------- K1: weight cast + K-permute, plus grid table ----------------
// wp[o][i*8+j] = bf16(w[o][j*512+i]) for j<8 ; wp[o][4096+i] = bf16(w[o][8*512+i])
__global__ __launch_bounds__(256) void cast_w_perm(const float* __restrict__ w,
                                                   short* __restrict__ wp,
                                                   const float* __restrict__ grid,
                                                   float2* __restrict__ tbl) {
    int blk = blockIdx.x;
    if (blk == 1024) {                                  // grid table: off = g0, scale = 5/(g5-g0)
        for (int i = threadIdx.x; i < IN_DIM; i += 256) {
            float g0 = grid[i * 6];
            float g5 = grid[i * 6 + 5];
            tbl[i] = make_float2(g0, 5.0f / (g5 - g0));
        }
        return;
    }
    int idx = blk * 256 + threadIdx.x;                  // (o,i)
    int o = idx >> 9;
    int i = idx & 511;
    const float* wo = w + (size_t)o * KDIM;
    bf16x8 v;
#pragma unroll
    for (int j = 0; j < 8; ++j) {
        __hip_bfloat16 h = __float2bfloat16(wo[j * 512 + i]);
        v[j] = *reinterpret_cast<short*>(&h);
    }
    *reinterpret_cast<bf16x8*>(wp + (size_t)o * KDIM + i * 8) = v;
    __hip_bfloat16 h8 = __float2bfloat16(wo[8 * 512 + i]);
    wp[(size_t)o * KDIM + 4096 + i] = *reinterpret_cast<short*>(&h8);
}

// ---------------- K2: fused acts-build + bf16 MFMA GEMM, split-K=4 ----------------
#define BM 128
#define BN 128
#define BK 64

__global__ __launch_bounds__(256) void gemm_fused(const float* __restrict__ x,
                                                  const short* __restrict__ Wp,
                                                  const float2* __restrict__ tbl,
                                                  _Float16* __restrict__ part) {
    __shared__ __align__(16) short As[BM * BK];    // 16 KB, XOR-swizzled 16B slots
    __shared__ __align__(16) short Ws[BN * BK];    // 16 KB

    // XCD-aware swizzle (bijective: 512 % 8 == 0)
    int nper = gridDim.x >> 3;
    int bid  = (blockIdx.x & 7) * nper + (blockIdx.x >> 3);
    int sk = bid >> 7;
    int mn = bid & 127;
    int bm = mn >> 2;             // 0..31
    int bn = mn & 3;              // 0..3

    int tid  = threadIdx.x;
    int lane = tid & 63;
    int wid  = tid >> 6;
    int wr   = wid >> 1;          // 64-row wave tile
    int wc   = wid & 1;           // 64-col wave tile

    const short* Wb = Wp + (size_t)(bn * BN) * KDIM + sk * KSPLIT;

    f32x4 acc[4][4];
#pragma unroll
    for (int m = 0; m < 4; ++m)
#pragma unroll
        for (int n = 0; n < 4; ++n) acc[m][n] = (f32x4){0.f, 0.f, 0.f, 0.f};

    // W staging (global_load_lds, inverse-swizzled source)
    int srow = lane >> 3;
    int scol = ((lane & 7) ^ srow) * 8;

    // A staging (computed, reg->LDS): thread owns row=tid>>1, slots sbase..sbase+3
    int arow  = tid >> 1;                       // 0..127
    int sbase = (tid & 1) * 4;
    int r7    = arow & 7;
    const float* xrow = x + (size_t)(bm * BM + arow) * IN_DIM;

    for (int kb = 0; kb < KSPLIT / BK; ++kb) {
        int k0l = kb * BK;
        int k0g = sk * KSPLIT + k0l;            // global permuted-K offset
        __syncthreads();                        // prev iter's LDS readers done

        // issue async W loads first (latency hides under A's VALU)
#pragma unroll
        for (int i = 0; i < 4; ++i) {
            int r0 = i * 32 + wid * 8;
            __builtin_amdgcn_global_load_lds(
                (const __attribute__((address_space(1))) void*)(Wb + (size_t)(r0 + srow) * KDIM + k0l + scol),
                (__attribute__((address_space(3))) void*)(&Ws[r0 * 64]),
                16, 0, 0);
        }

        // compute A tile: slot s holds data for col8 = s ^ (row&7)
        if (k0g < 4096) {                       // spline region: col8 = i-offset, elem = j
            int i0 = k0g >> 3;
#pragma unroll
            for (int c = 0; c < 4; ++c) {
                int s  = sbase + c;
                int ii = i0 + (s ^ r7);
                float xv = xrow[ii];
                float2 t = tbl[ii];
                float ss = (xv - t.x) * t.y;    // in [0,5)
                int mi = (int)ss; mi = mi < 0 ? 0 : (mi > 4 ? 4 : mi);
                float u  = ss - (float)mi;
                float u2 = u * u, u3 = u2 * u;
                float om = 1.0f - u;
                float xb = xv * (1.0f / 6.0f);
                float b0 = om * om * om * xb;
                float b1 = (3.0f * u3 - 6.0f * u2 + 4.0f) * xb;
                float b2 = (-3.0f * u3 + 3.0f * u2 + 3.0f * u + 1.0f) * xb;
                float b3 = u3 * xb;
                // place [b0..b3] at bf16 lanes mi..mi+3 of a 128-bit word
                unsigned long long p = pack4(b0, b1, b2, b3);
                unsigned sh = (unsigned)mi << 4;                    // 0,16,32,48,64
                unsigned long long l1 = p << (sh & 63);
                unsigned long long r1 = p >> ((64u - sh) & 63);
                unsigned long long lo = (sh == 64u) ? 0ull : l1;
                unsigned long long hi = (sh == 0u) ? 0ull : ((sh == 64u) ? p : r1);
                ulonglong2 v; v.x = lo; v.y = hi;
                *reinterpret_cast<ulonglong2*>(&As[arow * 64 + s * 8]) = v;
            }
        } else {                                // silu region: k' = 4096 + i
            int ib = k0g - 4096;
#pragma unroll
            for (int c = 0; c < 4; ++c) {
                int s = sbase + c;
                const float* xp = xrow + ib + (s ^ r7) * 8;
                float4 xa = *reinterpret_cast<const float4*>(xp);
                float4 xc = *reinterpret_cast<const float4*>(xp + 4);
                ulonglong2 v;
                v.x = pack4(silux(xa.x), silux(xa.y), silux(xa.z), silux(xa.w));
                v.y = pack4(silux(xc.x), silux(xc.y), silux(xc.z), silux(xc.w));
                *reinterpret_cast<ulonglong2*>(&As[arow * 64 + s * 8]) = v;
            }
        }
        __syncthreads();                        // vmcnt + lgkm drain: tiles ready

        int g  = lane >> 4;
        int fr = lane & 15;
#pragma unroll
        for (int ks = 0; ks < 2; ++ks) {
            int kk8 = ks * 4 + g;
            bf16x8 af[4], wf[4];
#pragma unroll
            for (int m = 0; m < 4; ++m) {
                int row = wr * 64 + m * 16 + fr;
                int slot = kk8 ^ (row & 7);
                af[m] = *reinterpret_cast<const bf16x8*>(&As[row * 64 + slot * 8]);
            }
#pragma unroll
            for (int n = 0; n < 4; ++n) {
                int col = wc * 64 + n * 16 + fr;
                int slot = kk8 ^ (col & 7);
                wf[n] = *reinterpret_cast<const bf16x8*>(&Ws[col * 64 + slot * 8]);
            }
#pragma unroll
            for (int m = 0; m < 4; ++m)
#pragma unroll
                for (int n = 0; n < 4; ++n)
                    acc[m][n] = __builtin_amdgcn_mfma_f32_16x16x32_bf16(af[m], wf[n], acc[m][n], 0, 0, 0);
        }
    }

    // epilogue: C/D col = lane&15, row = (lane>>4)*4 + reg; fp16 partials
    _Float16* p = part + (size_t)sk * BATCH * OUT_DIM;
    int crow0 = bm * BM + wr * 64 + (lane >> 4) * 4;
    int ccol0 = bn * BN + wc * 64 + (lane & 15);
#pragma unroll
    for (int m = 0; m < 4; ++m)
#pragma unroll
        for (int n = 0; n < 4; ++n)
#pragma unroll
            for (int r = 0; r < 4; ++r)
                p[(size_t)(crow0 + m * 16 + r) * OUT_DIM + ccol0 + n * 16] =
                    (_Float16)acc[m][n][r];
}

// ---------------- K3: reduce fp16 partials + bias ----------------
__global__ __launch_bounds__(256) void reduce_out(const _Float16* __restrict__ part,
                                                  const float4* __restrict__ bias,
                                                  float4* __restrict__ out) {
    int idx = blockIdx.x * 256 + threadIdx.x;     // 8 outputs each
    const size_t stride = (size_t)BATCH * OUT_DIM;
    float4 b0 = bias[(idx & 63) * 2];
    float4 b1 = bias[(idx & 63) * 2 + 1];
    float a[8] = {b0.x, b0.y, b0.z, b0.w, b1.x, b1.y, b1.z, b1.w};
#pragma unroll
    for (int s = 0; s < SPLITK; ++s) {
        h16x8 v = *reinterpret_cast<const h16x8*>(part + (size_t)s * stride + (size_t)idx * 8);
#pragma unroll
        for (int j = 0; j < 8; ++j) a[j] += (float)v[j];
    }
    out[idx * 2]     = (float4){a[0], a[1], a[2], a[3]};
    out[idx * 2 + 1] = (float4){a[4], a[5], a[6], a[7]};
}

extern "C" void kernel_launch(void* const* d_in, const int* in_sizes, int n_in,
                              void* d_out, int out_size, void* d_ws, size_t ws_size,
                              hipStream_t stream) {
    (void)in_sizes; (void)n_in; (void)out_size; (void)ws_size;
    const float* x      = (const float*)d_in[0];
    const float* grid   = (const float*)d_in[1];
    const float* weight = (const float*)d_in[2];
    const float* bias   = (const float*)d_in[3];

    char* ws = (char*)d_ws;
    short*    wbf  = (short*)(ws + WOFF_WBF);
    _Float16* part = (_Float16*)(ws + WOFF_PART);
    float2*   tbl  = (float2*)(ws + WOFF_TBL);

    cast_w_perm<<<1025, 256, 0, stream>>>(weight, wbf, grid, tbl);
    gemm_fused<<<128 * SPLITK, 256, 0, stream>>>(x, wbf, tbl, part);
    reduce_out<<<(BATCH * OUT_DIM / 8) / 256, 256, 0, stream>>>(
        part, (const float4*)bias, (float4*)d_out);
}

// Round 6
// 55.919 us; speedup vs baseline: 1.1584x; 1.1584x over previous
//
#include <hip/hip_runtime.h>
#include <hip/hip_bf16.h>

#define IN_DIM  512
#define OUT_DIM 512
#define BATCH   4096
#define KDIM    4608            // permuted: k' = i*8+j (j=0..7 splines), 4096+i = silu
#define SPLITK  4
#define KSPLIT  1152

// ws layout (bytes)
#define WOFF_WBF  0
#define WSZ_WBF   (OUT_DIM * KDIM * 2)                  // 4,718,592 (permuted bf16 W)
#define WOFF_PART (WOFF_WBF + WSZ_WBF)
#define WSZ_PART  (SPLITK * BATCH * OUT_DIM * 2)        // 16,777,216 (fp16 partials)
#define WOFF_TBL  (WOFF_PART + WSZ_PART)                // 512 float2 = 4 KB

typedef __attribute__((ext_vector_type(8))) short bf16x8;
typedef __attribute__((ext_vector_type(4))) float f32x4;
typedef __attribute__((ext_vector_type(8))) _Float16 h16x8;

__device__ __forceinline__ unsigned long long pack4(float a, float b, float c, float d) {
    __hip_bfloat16 ha = __float2bfloat16(a), hb = __float2bfloat16(b),
                   hc = __float2bfloat16(c), hd = __float2bfloat16(d);
    return  (unsigned long long)*reinterpret_cast<unsigned short*>(&ha)
         | ((unsigned long long)*reinterpret_cast<unsigned short*>(&hb) << 16)
         | ((unsigned long long)*reinterpret_cast<unsigned short*>(&hc) << 32)
         | ((unsigned long long)*reinterpret_cast<unsigned short*>(&hd) << 48);
}

__device__ __forceinline__ float silux(float z) {     // silu(z)*z
    return z * z / (1.0f + __expf(-z));
}

// ---------------- K1: weight cast + K-permute, plus grid table ----------------
// wp[o][i*8+j] = bf16(w[o][j*512+i]) for j<8 ; wp[o][4096+i] = bf16(w[o][8*512+i])
__global__ __launch_bounds__(256) void cast_w_perm(const float* __restrict__ w,
                                                   short* __restrict__ wp,
                                                   const float* __restrict__ grid,
                                                   float2* __restrict__ tbl) {
    int blk = blockIdx.x;
    if (blk == 1024) {                                  // grid table: off = g0, scale = 5/(g5-g0)
        for (int i = threadIdx.x; i < IN_DIM; i += 256) {
            float g0 = grid[i * 6];
            float g5 = grid[i * 6 + 5];
            tbl[i] = make_float2(g0, 5.0f / (g5 - g0));
        }
        return;
    }
    int idx = blk * 256 + threadIdx.x;                  // (o,i)
    int o = idx >> 9;
    int i = idx & 511;
    const float* wo = w + (size_t)o * KDIM;
    bf16x8 v;
#pragma unroll
    for (int j = 0; j < 8; ++j) {
        __hip_bfloat16 h = __float2bfloat16(wo[j * 512 + i]);
        v[j] = *reinterpret_cast<short*>(&h);
    }
    *reinterpret_cast<bf16x8*>(wp + (size_t)o * KDIM + i * 8) = v;
    __hip_bfloat16 h8 = __float2bfloat16(wo[8 * 512 + i]);
    wp[(size_t)o * KDIM + 4096 + i] = *reinterpret_cast<short*>(&h8);
}

// ---------------- K2: fused acts-build + bf16 MFMA GEMM ----------------
// 512 threads = 8 waves (2 wave-rows x 4 wave-cols), BM=128, BN=256, BK=64.
// grid = 256 blocks: logical l = sk*64 + bm*2 + bn (XCD-swizzled).
#define BM 128
#define BN 256
#define BK 64

__global__ __launch_bounds__(512) void gemm_fused(const float* __restrict__ x,
                                                  const short* __restrict__ Wp,
                                                  const float2* __restrict__ tbl,
                                                  _Float16* __restrict__ part) {
    __shared__ __align__(16) short As[BM * BK];    // 16 KB, XOR-swizzled 16B slots
    __shared__ __align__(16) short Ws[BN * BK];    // 32 KB

    // XCD-aware swizzle (bijective: 256 % 8 == 0); each XCD owns 32 logical
    // ids = one sk, 16 bm, both bn -> W panel 512x1152x2B = 1.18 MB L2-resident.
    int l  = (blockIdx.x & 7) * 32 + (blockIdx.x >> 3);
    int sk = l >> 6;
    int bm = (l & 63) >> 1;
    int bn = l & 1;

    int tid  = threadIdx.x;
    int lane = tid & 63;
    int wid  = tid >> 6;          // 0..7
    int wr   = wid >> 2;          // 0..1 (64-row wave tile)
    int wc   = wid & 3;           // 0..3 (64-col wave tile)

    const short* Wb = Wp + (size_t)(bn * BN) * KDIM + sk * KSPLIT;

    f32x4 acc[4][4];
#pragma unroll
    for (int m = 0; m < 4; ++m)
#pragma unroll
        for (int n = 0; n < 4; ++n) acc[m][n] = (f32x4){0.f, 0.f, 0.f, 0.f};

    // W staging (global_load_lds, inverse-swizzled source)
    int srow = lane >> 3;                       // 0..7
    int scol = ((lane & 7) ^ srow) * 8;

    // A build: thread owns row = tid>>2, data cols col8 in {(tid&3)*2, +1};
    // write slot = col8 ^ (row&7)  (both-sides swizzle, matches read)
    int arow  = tid >> 2;                       // 0..127
    int cpair = (tid & 3) * 2;
    int r7    = arow & 7;
    const float* xrow = x + (size_t)(bm * BM + arow) * IN_DIM;

    for (int kb = 0; kb < KSPLIT / BK; ++kb) {
        int k0l = kb * BK;
        int k0g = sk * KSPLIT + k0l;            // global permuted-K offset
        __syncthreads();                        // prev iter's LDS readers done

        // issue async W loads first (latency hides under A's VALU)
#pragma unroll
        for (int i = 0; i < 4; ++i) {
            int r0 = i * 64 + wid * 8;
            __builtin_amdgcn_global_load_lds(
                (const __attribute__((address_space(1))) void*)(Wb + (size_t)(r0 + srow) * KDIM + k0l + scol),
                (__attribute__((address_space(3))) void*)(&Ws[r0 * 64]),
                16, 0, 0);
        }

        // compute A tile (2 slots of 8 bf16 per thread)
        if (k0g < 4096) {                       // spline region: col8 = i-offset, elem = j
            int i0 = k0g >> 3;
#pragma unroll
            for (int c = 0; c < 2; ++c) {
                int col8 = cpair + c;
                int ii = i0 + col8;
                float xv = xrow[ii];
                float2 t = tbl[ii];
                float ss = (xv - t.x) * t.y;    // in [0,5)
                int mi = (int)ss; mi = mi < 0 ? 0 : (mi > 4 ? 4 : mi);
                float u  = ss - (float)mi;
                float u2 = u * u, u3 = u2 * u;
                float om = 1.0f - u;
                float xb = xv * (1.0f / 6.0f);
                float b0 = om * om * om * xb;
                float b1 = (3.0f * u3 - 6.0f * u2 + 4.0f) * xb;
                float b2 = (-3.0f * u3 + 3.0f * u2 + 3.0f * u + 1.0f) * xb;
                float b3 = u3 * xb;
                // place [b0..b3] at bf16 lanes mi..mi+3 of a 128-bit word
                unsigned long long p = pack4(b0, b1, b2, b3);
                unsigned sh = (unsigned)mi << 4;                    // 0,16,32,48,64
                unsigned long long l1 = p << (sh & 63);
                unsigned long long r1 = p >> ((64u - sh) & 63);
                unsigned long long lo = (sh == 64u) ? 0ull : l1;
                unsigned long long hi = (sh == 0u) ? 0ull : ((sh == 64u) ? p : r1);
                ulonglong2 v; v.x = lo; v.y = hi;
                int slot = col8 ^ r7;
                *reinterpret_cast<ulonglong2*>(&As[arow * 64 + slot * 8]) = v;
            }
        } else {                                // silu region: k' = 4096 + i
            int ib = k0g - 4096;
#pragma unroll
            for (int c = 0; c < 2; ++c) {
                int col8 = cpair + c;
                const float* xp = xrow + ib + col8 * 8;
                float4 xa = *reinterpret_cast<const float4*>(xp);
                float4 xc = *reinterpret_cast<const float4*>(xp + 4);
                ulonglong2 v;
                v.x = pack4(silux(xa.x), silux(xa.y), silux(xa.z), silux(xa.w));
                v.y = pack4(silux(xc.x), silux(xc.y), silux(xc.z), silux(xc.w));
                int slot = col8 ^ r7;
                *reinterpret_cast<ulonglong2*>(&As[arow * 64 + slot * 8]) = v;
            }
        }
        __syncthreads();                        // vmcnt + lgkm drain: tiles ready

        int g  = lane >> 4;
        int fr = lane & 15;
#pragma unroll
        for (int ks = 0; ks < 2; ++ks) {
            int kk8 = ks * 4 + g;
            bf16x8 af[4], wf[4];
#pragma unroll
            for (int m = 0; m < 4; ++m) {
                int row = wr * 64 + m * 16 + fr;
                int slot = kk8 ^ (row & 7);
                af[m] = *reinterpret_cast<const bf16x8*>(&As[row * 64 + slot * 8]);
            }
#pragma unroll
            for (int n = 0; n < 4; ++n) {
                int col = wc * 64 + n * 16 + fr;
                int slot = kk8 ^ (col & 7);
                wf[n] = *reinterpret_cast<const bf16x8*>(&Ws[col * 64 + slot * 8]);
            }
#pragma unroll
            for (int m = 0; m < 4; ++m)
#pragma unroll
                for (int n = 0; n < 4; ++n)
                    acc[m][n] = __builtin_amdgcn_mfma_f32_16x16x32_bf16(af[m], wf[n], acc[m][n], 0, 0, 0);
        }
    }

    // epilogue: C/D col = lane&15, row = (lane>>4)*4 + reg; fp16 partials
    _Float16* p = part + (size_t)sk * BATCH * OUT_DIM;
    int crow0 = bm * BM + wr * 64 + (lane >> 4) * 4;
    int ccol0 = bn * BN + wc * 64 + (lane & 15);
#pragma unroll
    for (int m = 0; m < 4; ++m)
#pragma unroll
        for (int n = 0; n < 4; ++n)
#pragma unroll
            for (int r = 0; r < 4; ++r)
                p[(size_t)(crow0 + m * 16 + r) * OUT_DIM + ccol0 + n * 16] =
                    (_Float16)acc[m][n][r];
}

// ---------------- K3: reduce fp16 partials + bias ----------------
__global__ __launch_bounds__(256) void reduce_out(const _Float16* __restrict__ part,
                                                  const float4* __restrict__ bias,
                                                  float4* __restrict__ out) {
    int idx = blockIdx.x * 256 + threadIdx.x;     // 8 outputs each
    const size_t stride = (size_t)BATCH * OUT_DIM;
    float4 b0 = bias[(idx & 63) * 2];
    float4 b1 = bias[(idx & 63) * 2 + 1];
    float a[8] = {b0.x, b0.y, b0.z, b0.w, b1.x, b1.y, b1.z, b1.w};
#pragma unroll
    for (int s = 0; s < SPLITK; ++s) {
        h16x8 v = *reinterpret_cast<const h16x8*>(part + (size_t)s * stride + (size_t)idx * 8);
#pragma unroll
        for (int j = 0; j < 8; ++j) a[j] += (float)v[j];
    }
    out[idx * 2]     = (float4){a[0], a[1], a[2], a[3]};
    out[idx * 2 + 1] = (float4){a[4], a[5], a[6], a[7]};
}

extern "C" void kernel_launch(void* const* d_in, const int* in_sizes, int n_in,
                              void* d_out, int out_size, void* d_ws, size_t ws_size,
                              hipStream_t stream) {
    (void)in_sizes; (void)n_in; (void)out_size; (void)ws_size;
    const float* x      = (const float*)d_in[0];
    const float* grid   = (const float*)d_in[1];
    const float* weight = (const float*)d_in[2];
    const float* bias   = (const float*)d_in[3];

    char* ws = (char*)d_ws;
    short*    wbf  = (short*)(ws + WOFF_WBF);
    _Float16* part = (_Float16*)(ws + WOFF_PART);
    float2*   tbl  = (float2*)(ws + WOFF_TBL);

    cast_w_perm<<<1025, 256, 0, stream>>>(weight, wbf, grid, tbl);
    gemm_fused<<<256, 512, 0, stream>>>(x, wbf, tbl, part);
    reduce_out<<<(BATCH * OUT_DIM / 8) / 256, 256, 0, stream>>>(
        part, (const float4*)bias, (float4*)d_out);
}